// Round 1
// 428.852 us; speedup vs baseline: 1.3101x; 1.3101x over previous
//
#include <hip/hip_runtime.h>
#include <hip/hip_bf16.h>
#include <math.h>

// ---------------------------------------------------------------------------
// MjCambrianOptics. Correctness-critical (R7-validated, DO NOT TOUCH):
//   * mean(depth) = numpy BUFFERED reduce: seed a[0], then sequential
//     += pairwise_sum(8192-chunk), 128-leaf/8-acc recursion.
//   * ki = fl32(2pi)/fl32(wl) f32 divide; linspace f64-cast; th/ph op order.
// R11: conv -> MFMA (banded-Toeplitz implicit GEMM, split-bf16 hi/lo, no LDS).
// R12: k_conv latency fix — 4-wave blocks, image tile staged in LDS (stride
//      312 = conflict-free ds_read_b128), 3 accumulators, VGPR headroom.
// ---------------------------------------------------------------------------

constexpr int M   = 255;
constexpr int NP  = M * M;        // 65025
constexpr int RESO = 160;

// IMG2 (padded bf16 image, hi|lo): [side][ch][row 0..415][col 0..447]
constexpr int IMG_ROWS = 416, IMG_COLS = 448;
constexpr int IMG_CH   = IMG_ROWS * IMG_COLS;      // 186368
constexpr int IMG_SIDE = 3 * IMG_CH;               // 559104
// P4 (4-shift-copy padded bf16 psf, hi|lo): [side][ch][di 0..255][r 0..3][e 0..319]
constexpr int P4_DI   = 4 * 320;                   // 1280
constexpr int P4_CH   = 256 * P4_DI;               // 327680
constexpr int P4_SIDE = 3 * P4_CH;                 // 983040

typedef __attribute__((ext_vector_type(8))) short short8;
typedef __attribute__((ext_vector_type(4))) float f32x4;

__device__ __forceinline__ unsigned short f2bf(float f) {
    unsigned int u = __float_as_uint(f);
    unsigned int r = (u + 0x7fffu + ((u >> 16) & 1u)) >> 16;
    return (unsigned short)r;
}
__device__ __forceinline__ float bf2f(unsigned short h) {
    return __uint_as_float(((unsigned int)h) << 16);
}

// ---------------- numpy buffered-reduce pairwise forest (compile-time) ------
constexpr int MAXN = 1100;
struct PWForest {
    int kind[MAXN];
    int off[MAXN], len[MAXN];
    int li[MAXN], ri[MAXN];
    int lvl[MAXN];
    int nNode, nLeaf, maxLvl;
    int roots[16], nRoots;
};
constexpr int pwf_build(PWForest& T, int o, int n) {
    if (n <= 128) {
        int id = T.nNode++;
        T.kind[id] = 0; T.off[id] = o; T.len[id] = n;
        T.lvl[id] = 0; T.nLeaf++;
        return id;
    }
    int n2 = (n / 2) - ((n / 2) % 8);
    int a = pwf_build(T, o, n2);
    int b = pwf_build(T, o + n2, n - n2);
    int id = T.nNode++;
    T.kind[id] = 1; T.li[id] = a; T.ri[id] = b;
    int l = (T.lvl[a] > T.lvl[b] ? T.lvl[a] : T.lvl[b]) + 1;
    T.lvl[id] = l; if (l > T.maxLvl) T.maxLvl = l;
    return id;
}
constexpr PWForest pwf_make() {
    PWForest T{};
    int pos = 1, rem = NP - 1;            // reduce seeds with a[0]
    while (rem > 0) {
        int c = rem > 8192 ? 8192 : rem;  // nditer buffer = 8192 elements
        T.roots[T.nRoots++] = pwf_build(T, pos, c);
        pos += c; rem -= c;
    }
    return T;
}
constexpr PWForest PW = pwf_make();
static_assert(PW.nNode <= MAXN, "forest overflow");
static_assert(PW.nRoots == 8, "chunk count");

__global__ void k_mean(const float* __restrict__ depth, float* __restrict__ meanp) {
    __shared__ float val[MAXN];
    int tid = threadIdx.x;
    for (int id = tid; id < PW.nNode; id += 256) {
        if (PW.kind[id] != 0) continue;
        const float* a = depth + PW.off[id];
        int n = PW.len[id];
        float r0 = a[0], r1 = a[1], r2 = a[2], r3 = a[3];
        float r4 = a[4], r5 = a[5], r6 = a[6], r7 = a[7];
        int lim = n - (n % 8);
        int i = 8;
        for (; i < lim; i += 8) {
            r0 += a[i + 0]; r1 += a[i + 1]; r2 += a[i + 2]; r3 += a[i + 3];
            r4 += a[i + 4]; r5 += a[i + 5]; r6 += a[i + 6]; r7 += a[i + 7];
        }
        float res = ((r0 + r1) + (r2 + r3)) + ((r4 + r5) + (r6 + r7));
        for (; i < n; ++i) res += a[i];
        val[id] = res;
    }
    __syncthreads();
    for (int l = 1; l <= PW.maxLvl; ++l) {
        for (int id = tid; id < PW.nNode; id += 256)
            if (PW.kind[id] == 1 && PW.lvl[id] == l)
                val[id] = val[PW.li[id]] + val[PW.ri[id]];
        __syncthreads();
    }
    if (tid == 0) {
        float io1 = depth[0];
        for (int r = 0; r < PW.nRoots; ++r)
            io1 = io1 + val[PW.roots[r]];
        meanp[0] = io1 / 65025.0f;
    }
}

// ---------------- prep: u2H fields + DFT W + padded bf16 image --------------
__global__ void k_prep(const float* __restrict__ img, unsigned short* __restrict__ IMG2,
                       float2* __restrict__ W,
                       float2* __restrict__ U2, float2* __restrict__ Hb,
                       const float* __restrict__ meanp,
                       double xstart, double xstep, double xstop,
                       double fstart, double fstep, double fstop,
                       float ap_f) {
#pragma clang fp contract(off)
    int idx = blockIdx.x * 256 + threadIdx.x;
    if (idx < 3 * NP) {
        int c = idx / NP, ij = idx % NP, i = ij / M, j = ij % M;
        const float wls[3] = {6.1e-07f, 5.3e-07f, 4.7e-07f};
        float wl = wls[c];
        float ki = ((float)6.283185307179586) / wl;
        float d  = meanp[0];
        float d2 = d * d;

        float x  = (i == 254) ? (float)xstop : (float)((double)i * xstep + xstart);
        float y  = (j == 254) ? (float)xstop : (float)((double)j * xstep + xstart);
        float fx = (i == 254) ? (float)fstop : (float)((double)i * fstep + fstart);
        float fy = (j == 254) ? (float)fstop : (float)((double)j * fstep + fstart);

        float xx = x * x, yy = y * y;
        float X1Y1 = xx + yy;

        float s  = sqrtf(X1Y1 + d2);
        float th = ki * s;
        float A  = (sqrtf(X1Y1) / ap_f <= 1.0f) ? 1.0f : 0.0f;
        float2 u2v;
        if (A != 0.0f) u2v = make_float2((float)cos((double)th), (float)sin((double)th));
        else           u2v = make_float2(0.0f, 0.0f);

        float a = wl * fx, b = wl * fy;
        float arg = (1.0f - a * a) - b * b;
        float FXY = sqrtf(fmaxf(arg, 0.0f));
        float Hv  = (sqrtf(fx * fx + fy * fy) < (1.0f / wl)) ? 1.0f : 0.0f;
        float kd  = ki * d;
        float ph  = kd * FXY;
        float cph = (float)cos((double)ph), sph = (float)sin((double)ph);
        float2 hv = make_float2(Hv * cph, Hv * sph);

        U2[idx] = u2v;
        Hb[idx] = hv;
        return;
    }
    if (idx < 4 * NP) {
        int e = idx - 3 * NP;
        int n = e / M, k = e % M;
        int m = (n * k) % M;
        double ang = -2.0 * 3.14159265358979323846 * (double)m / 255.0;
        W[e] = make_float2((float)cos(ang), (float)sin(ang));
        return;
    }
    int e = idx - 4 * NP;
    if (e >= IMG_SIDE) return;
    int ch = e / IMG_CH, rem = e % IMG_CH;
    int prow = rem / IMG_COLS, pcol = rem % IMG_COLS;
    int a = prow - 80, b = pcol - 80;
    float v = 0.0f;
    if (a >= 0 && a < M && b >= 0 && b < M) v = img[(a * M + b) * 3 + ch];
    unsigned short hi = f2bf(v);
    unsigned short lo = f2bf(v - bf2f(hi));
    IMG2[e] = hi;
    IMG2[IMG_SIDE + e] = lo;
}

// ---------------- batched f32 complex GEMM, 32x32 tile, 2x2/thread ----------
__global__ __launch_bounds__(256)
void k_cgemm(const float2* __restrict__ A, int aBatch,
             const float2* __restrict__ B, const float2* __restrict__ B2,
             int bBatch, float2* __restrict__ C,
             int conjA, int conjB, float scale) {
    __shared__ float2 As[32][17];
    __shared__ float2 Bs[16][33];
    int c = blockIdx.z;
    int tx = threadIdx.x & 15, ty = threadIdx.x >> 4;
    int i0 = blockIdx.y * 32, j0 = blockIdx.x * 32;
    const float2* Ab = A + (size_t)c * aBatch;
    const float2* Bb = B + (size_t)c * bBatch;
    const float2* B2b = B2 ? (B2 + (size_t)c * bBatch) : nullptr;
    float2 a00 = {0,0}, a01 = {0,0}, a10 = {0,0}, a11 = {0,0};

    for (int kt = 0; kt < 16; ++kt) {
        int k0 = kt * 16;
#pragma unroll
        for (int s = 0; s < 2; ++s) {
            int idx = threadIdx.x + s * 256;
            int r = idx >> 4, cc = idx & 15;
            int gi = i0 + r, gk = k0 + cc;
            float2 v = (gi < M && gk < M) ? Ab[gi * M + gk] : make_float2(0.f, 0.f);
            if (conjA) v.y = -v.y;
            As[r][cc] = v;
            int r2 = idx >> 5, c2 = idx & 31;
            int gk2 = k0 + r2, gj = j0 + c2;
            float2 w = make_float2(0.f, 0.f);
            if (gk2 < M && gj < M) {
                w = Bb[gk2 * M + gj];
                if (B2b) {
                    float2 z = B2b[gk2 * M + gj];
                    w = make_float2(w.x * z.x - w.y * z.y, w.x * z.y + w.y * z.x);
                }
            }
            if (conjB) w.y = -w.y;
            Bs[r2][c2] = w;
        }
        __syncthreads();
#pragma unroll
        for (int kk = 0; kk < 16; ++kk) {
            float2 p = As[ty][kk], q = As[ty + 16][kk];
            float2 u = Bs[kk][tx], v = Bs[kk][tx + 16];
            a00.x += p.x * u.x - p.y * u.y;  a00.y += p.x * u.y + p.y * u.x;
            a01.x += p.x * v.x - p.y * v.y;  a01.y += p.x * v.y + p.y * v.x;
            a10.x += q.x * u.x - q.y * u.y;  a10.y += q.x * u.y + q.y * u.x;
            a11.x += q.x * v.x - q.y * v.y;  a11.y += q.x * v.y + q.y * v.x;
        }
        __syncthreads();
    }
    float2* Cb = C + (size_t)c * NP;
    int gi0 = i0 + ty, gi1 = i0 + ty + 16;
    int gj0 = j0 + tx, gj1 = j0 + tx + 16;
    if (gi0 < M && gj0 < M) Cb[gi0 * M + gj0] = make_float2(a00.x * scale, a00.y * scale);
    if (gi0 < M && gj1 < M) Cb[gi0 * M + gj1] = make_float2(a01.x * scale, a01.y * scale);
    if (gi1 < M && gj0 < M) Cb[gi1 * M + gj0] = make_float2(a10.x * scale, a10.y * scale);
    if (gi1 < M && gj1 < M) Cb[gi1 * M + gj1] = make_float2(a11.x * scale, a11.y * scale);
}

// ---------------- S = sum u3^2 (f64 accumulate over f32 u3) ----------------
__global__ void k_sred(const float2* __restrict__ U3, double2* __restrict__ spart) {
    __shared__ double sx[256], sy[256];
    int t = threadIdx.x;
    double ax = 0.0, ay = 0.0;
    for (int i = blockIdx.x * 256 + t; i < 3 * NP; i += 64 * 256) {
        double zx = (double)U3[i].x, zy = (double)U3[i].y;
        ax += zx * zx - zy * zy;
        ay += 2.0 * zx * zy;
    }
    sx[t] = ax; sy[t] = ay;
    __syncthreads();
    for (int w = 128; w > 0; w >>= 1) {
        if (t < w) { sx[t] += sx[t + w]; sy[t] += sy[t + w]; }
        __syncthreads();
    }
    if (t == 0) spart[blockIdx.x] = make_double2(sx[0], sy[0]);
}

// ---------------- psf -> P4 (4-shift-copy bf16 hi/lo band table) ------------
__global__ void k_p4(const float2* __restrict__ U3, const double2* __restrict__ spart,
                     unsigned short* __restrict__ P4) {
    int idx = blockIdx.x * 256 + threadIdx.x;
    if (idx >= P4_SIDE) return;
    double rx = 0.0, ry = 0.0;
    for (int i = 0; i < 64; ++i) { rx += spart[i].x; ry += spart[i].y; }
    double dsx = rx + 1e-7, dsy = ry;            // same association as before
    int ch = idx / P4_CH, rem = idx % P4_CH;
    int di = rem / P4_DI, rem2 = rem % P4_DI;
    int r = rem2 / 320, e = rem2 % 320;
    int u = e - 16 + r;
    float v = 0.0f;
    if (di < M && u >= 0 && u < M) {
        double inv = 1.0 / (dsx * dsx + dsy * dsy);
        float2 zf = U3[(ch * M + di) * M + u];
        double zx = (double)zf.x, zy = (double)zf.y;
        double zr = zx * zx - zy * zy;
        double zi = 2.0 * zx * zy;
        v = (float)((zr * dsx + zi * dsy) * inv);
    }
    unsigned short hi = f2bf(v);
    unsigned short lo = f2bf(v - bf2f(hi));
    P4[idx] = hi;
    P4[P4_SIDE + idx] = lo;
}

// ---------------- MFMA conv: banded-Toeplitz implicit GEMM ------------------
// Block = 256 threads = 4 waves, one 16x16 output tile, one (ch, 16-di chunk).
// Wave w handles di = d0 + 4w + t (t=0..3). Image tile (31 rows x 288 cols,
// hi+lo bf16) staged in LDS once per block; row stride 312 shorts (624 B =
// 156 dwords, 156 mod 32 = 28 -> 8 distinct bank quads over 16 rows -> free
// 2-way aliasing on ds_read_b128). psf band (A) stays global (L1/L2-hot,
// shared by all 100 (i0,j0) blocks of the same z-plane).
// 3 accumulators (HH/HL/LH) break the MFMA dependency chain; cross-wave
// partials summed through LDS, so PART layout / k_out are unchanged.
// C[m][n] += sum_k A[m][k] * B[k][n];  A = psf band, B = img rows.
// A[m=lane&15][k=8q+t] = psf[di][32c + 8q + t - m]   (from P4 shifted copies)
// B[k=8q+t][n=lane&15] = img[i0+n+di-80][j0-80+32c+8q+t]
// D: row(=m/j) = 4q+reg, col(=n/i) = lane&15.
constexpr int LDS_STRIDE = 312;    // shorts; 624 B rows, 16B aligned
__global__ __launch_bounds__(256, 4)
void k_conv(const unsigned short* __restrict__ IMG2,
            const unsigned short* __restrict__ P4,
            float* __restrict__ PART) {
    __shared__ __align__(16) unsigned short ldsI[2][31][LDS_STRIDE];

    int tid  = threadIdx.x;
    int w    = tid >> 6;           // wave 0..3
    int lane = tid & 63;
    int ln   = lane & 15;          // m for A, n for B/C-col
    int q    = lane >> 4;          // 0..3
    int j0 = blockIdx.x * 16;
    int i0 = blockIdx.y * 16;
    int bz = blockIdx.z;           // ch*16 + chunk
    int ch = bz >> 4, chunk = bz & 15;
    int d0 = chunk << 4;

    const unsigned short* imgH = IMG2 + ch * IMG_CH;
    const unsigned short* imgL = imgH + IMG_SIDE;
    const unsigned short* pHc  = P4 + ch * P4_CH;
    const unsigned short* pLc  = pHc + P4_SIDE;

    // ---- stage image tile: rows i0+d0 .. +30, cols j0 .. j0+287, hi+lo ----
    int row0 = i0 + d0;
    for (int idx = tid; idx < 2 * 31 * 36; idx += 256) {
        int plane = idx / (31 * 36);
        int rem = idx - plane * (31 * 36);
        int r = rem / 36, c = rem - r * 36;
        const unsigned short* src =
            (plane ? imgL : imgH) + (size_t)(row0 + r) * IMG_COLS + j0 + c * 8;
        *(short8*)&ldsI[plane][r][c * 8] = *(const short8*)src;
    }
    __syncthreads();

    f32x4 aHH = {0.f, 0.f, 0.f, 0.f};
    f32x4 aHL = {0.f, 0.f, 0.f, 0.f};
    f32x4 aLH = {0.f, 0.f, 0.f, 0.f};

    for (int t = 0; t < 4; ++t) {
        int dloc = 4 * w + t;
        int di = d0 + dloc;
        const unsigned short* prH = pHc + di * P4_DI;
        const unsigned short* prL = pLc + di * P4_DI;
        int rrow = ln + dloc;                  // LDS row for B (0..30)
#pragma unroll
        for (int cc = 0; cc < 9; ++cc) {
            int s  = 32 * cc + 8 * q - ln;     // A band start (dj space)
            int su = s + 16;
            int rb = su & 3;
            int e  = su - rb;
            const unsigned short* pa = prH + rb * 320 + e;
            const unsigned short* pl = prL + rb * 320 + e;
            ushort4 a0 = *(const ushort4*)(pa);
            ushort4 a1 = *(const ushort4*)(pa + 4);
            ushort4 l0 = *(const ushort4*)(pl);
            ushort4 l1 = *(const ushort4*)(pl + 4);
            int pcol = 32 * cc + 8 * q;        // tile-relative col (16B aligned)
            short8 bh = *(const short8*)&ldsI[0][rrow][pcol];
            short8 bl = *(const short8*)&ldsI[1][rrow][pcol];
            short8 ah, al;
            ah[0] = (short)a0.x; ah[1] = (short)a0.y; ah[2] = (short)a0.z; ah[3] = (short)a0.w;
            ah[4] = (short)a1.x; ah[5] = (short)a1.y; ah[6] = (short)a1.z; ah[7] = (short)a1.w;
            al[0] = (short)l0.x; al[1] = (short)l0.y; al[2] = (short)l0.z; al[3] = (short)l0.w;
            al[4] = (short)l1.x; al[5] = (short)l1.y; al[6] = (short)l1.z; al[7] = (short)l1.w;
            aHH = __builtin_amdgcn_mfma_f32_16x16x32_bf16(ah, bh, aHH, 0, 0, 0);
            aHL = __builtin_amdgcn_mfma_f32_16x16x32_bf16(ah, bl, aHL, 0, 0, 0);
            aLH = __builtin_amdgcn_mfma_f32_16x16x32_bf16(al, bh, aLH, 0, 0, 0);
        }
    }

    // ---- combine the three precision terms, then reduce across the 4 waves
    f32x4 tot;
#pragma unroll
    for (int r = 0; r < 4; ++r) tot[r] = aHH[r] + aHL[r] + aLH[r];

    __syncthreads();                       // everyone done reading image LDS
    float* red = (float*)&ldsI[0][0][0];
    if (w) {
#pragma unroll
        for (int r = 0; r < 4; ++r)
            red[((w - 1) * 64 + lane) * 4 + r] = tot[r];
    }
    __syncthreads();
    if (w == 0) {
#pragma unroll
        for (int wv = 0; wv < 3; ++wv)
#pragma unroll
            for (int r = 0; r < 4; ++r)
                tot[r] += red[(wv * 64 + lane) * 4 + r];
        // D row = 4q+reg -> j = j0+4q+reg ; D col = ln -> i = i0+ln
        float* op = PART + (size_t)bz * (RESO * RESO) + (i0 + ln) * RESO + j0 + 4 * q;
        float4 o; o.x = tot[0]; o.y = tot[1]; o.z = tot[2]; o.w = tot[3];
        *(float4*)op = o;
    }
}

// ---------------- reduce partials + clip + layout (i,j,c) ----------------
__global__ void k_out(const float* __restrict__ PART, float* __restrict__ out) {
    int idx = blockIdx.x * 256 + threadIdx.x;
    if (idx >= 3 * RESO * RESO) return;
    int c = idx / (RESO * RESO), ij = idx % (RESO * RESO);
    float s = 0.0f;
    for (int kz = 0; kz < 16; ++kz)
        s += PART[(size_t)(c * 16 + kz) * (RESO * RESO) + ij];
    s = fminf(fmaxf(s, 0.0f), 1.0f);
    int i = ij / RESO, j = ij % RESO;
    out[(i * RESO + j) * 3 + c] = s;
}

// ---------------------------------------------------------------------------
extern "C" void kernel_launch(void* const* d_in, const int* in_sizes, int n_in,
                              void* d_out, int out_size, void* d_ws, size_t ws_size,
                              hipStream_t stream) {
    const float* image = (const float*)d_in[0];   // (255,255,3)
    const float* depth = (const float*)d_in[1];   // (255,255)
    float* out = (float*)d_out;                   // (160,160,3)

    // workspace carve (256B aligned), ~22.5 MB
    char* p = (char*)d_ws;
    auto alloc = [&](size_t bytes) { void* r = (void*)p; p += (bytes + 255) & ~(size_t)255; return r; };
    float*   meanp = (float*)alloc(4);
    float2*  Wf    = (float2*)alloc((size_t)NP * 8);
    float2*  UH    = (float2*)alloc((size_t)6 * NP * 8);   // U2 | Hb
    float2*  Td    = (float2*)alloc((size_t)6 * NP * 8);
    float2*  EF    = (float2*)alloc((size_t)6 * NP * 8);   // FU | FH
    float2*  U3    = (float2*)alloc((size_t)3 * NP * 8);
    double2* spart = (double2*)alloc(64 * 16);
    unsigned short* P4   = (unsigned short*)alloc((size_t)2 * P4_SIDE * 2);
    unsigned short* IMG2 = (unsigned short*)alloc((size_t)2 * IMG_SIDE * 2);
    float*   PART  = (float*)alloc((size_t)48 * RESO * RESO * 4);

    float2* U2 = UH;
    float2* Hb = UH + (size_t)3 * NP;

    // exact python-f64 scalar path
    double dx = 0.002 / 255.0;
    double Lx = dx * 255.0;
    double ap = (Lx / 2.0) * 0.1 + 1e-7;
    float ap_f = (float)ap;

    double xstart = -(Lx / 2.0);
    double xstop  =  Lx / 2.0;
    double xstep  = (xstop - xstart) / 254.0;
    double fstart = -1.0 / (2.0 * dx);
    double fstop  =  1.0 / (2.0 * dx);
    double fstep  = (fstop - fstart) / 254.0;

    k_mean<<<1, 256, 0, stream>>>(depth, meanp);
    int gprep = (4 * NP + IMG_SIDE + 255) / 256;   // 3201
    k_prep<<<gprep, 256, 0, stream>>>(image, IMG2, Wf, U2, Hb, meanp,
                                      xstart, xstep, xstop,
                                      fstart, fstep, fstop, ap_f);

    dim3 bb(256);
    k_cgemm<<<dim3(8, 8, 6), bb, 0, stream>>>(Wf, 0, UH, nullptr, NP, Td, 0, 0, 1.0f);
    k_cgemm<<<dim3(8, 8, 6), bb, 0, stream>>>(Td, NP, Wf, nullptr, 0, EF, 0, 0, 1.0f);
    k_cgemm<<<dim3(8, 8, 3), bb, 0, stream>>>(Wf, 0, EF + (size_t)3 * NP, EF, NP,
                                              Td, 1, 0, 1.0f / 255.0f);
    k_cgemm<<<dim3(8, 8, 3), bb, 0, stream>>>(Td, NP, Wf, nullptr, 0, U3, 0, 1,
                                              1.0f / 255.0f);

    k_sred<<<64, 256, 0, stream>>>(U3, spart);
    k_p4<<<(P4_SIDE + 255) / 256, 256, 0, stream>>>(U3, spart, P4);

    k_conv<<<dim3(10, 10, 48), 256, 0, stream>>>(IMG2, P4, PART);
    k_out<<<300, 256, 0, stream>>>(PART, out);
}